// Round 5
// baseline (1188.696 us; speedup 1.0000x reference)
//
#include <hip/hip_runtime.h>
#include <math.h>

#define NNODES 8192
#define DDIM   64
#define NLAYER 9
#define NMLP   3

typedef short bfrag8 __attribute__((ext_vector_type(8)));   // 8 bf16 = 4 VGPR
typedef float facc16 __attribute__((ext_vector_type(16)));  // 32x32 C/D

// ---------------- weight transpose prep (once per launch) ----------------
__global__ void prep_weights(const float* __restrict__ conv_W,
                             const float* __restrict__ gru_Whh,
                             const float* __restrict__ gru_Wih,
                             const float* __restrict__ mlp_W,
                             float* __restrict__ WtA,
                             float* __restrict__ WtI,
                             float* __restrict__ WtM)
{
    int tid = blockIdx.x * blockDim.x + threadIdx.x;
    const int nA = NLAYER * 64 * 256;   // 147456
    const int nI = NLAYER * 64 * 192;   // 110592
    const int nM = NMLP * 64 * 64;      // 12288
    if (tid < nA) {
        int l = tid / 16384, rem = tid % 16384;
        int k = rem / 256, c = rem % 256;
        float v = (c < 64) ? conv_W[l * 4096 + c * 64 + k]
                           : gru_Whh[l * 12288 + (c - 64) * 64 + k];
        WtA[tid] = v;
    } else if (tid < nA + nI) {
        int t = tid - nA;
        int l = t / 12288, rem = t % 12288;
        int k = rem / 192, c = rem % 192;
        WtI[t] = gru_Wih[l * 12288 + c * 64 + k];
    } else if (tid < nA + nI + nM) {
        int t = tid - nA - nI;
        int m = t / 4096, rem = t % 4096;
        int k = rem / 64, c = rem % 64;
        WtM[t] = mlp_W[m * 4096 + c * 64 + k];
    }
}

// ---------------- h0 init + degree-count zero ----------------
__global__ void init_h(const float* __restrict__ node_feat,
                       float* __restrict__ h, int* __restrict__ counts)
{
    int tid = blockIdx.x * blockDim.x + threadIdx.x;
    if (tid < NNODES * DDIM) {
        int n = tid >> 6, d = tid & 63;
        h[tid] = (d == 0) ? node_feat[n] : 0.f;
    }
    if (tid < NNODES) counts[tid] = 0;
}

// ---------------- CSC build (by dst) ----------------
__global__ void count_deg(const int* __restrict__ dst, int E, int* __restrict__ counts)
{
    int tid = blockIdx.x * blockDim.x + threadIdx.x;
    if (tid < E) atomicAdd(&counts[dst[tid]], 1);
}

__global__ void scan_deg(const int* __restrict__ counts,
                         int* __restrict__ row_ptr, int* __restrict__ row_fill)
{
    __shared__ int partial[256];
    int t = threadIdx.x;
    int local[32];
    int base = t * 32;
    int s = 0;
    #pragma unroll
    for (int i = 0; i < 32; i++) { local[i] = counts[base + i]; s += local[i]; }
    partial[t] = s;
    __syncthreads();
    for (int off = 1; off < 256; off <<= 1) {
        int v = (t >= off) ? partial[t - off] : 0;
        __syncthreads();
        partial[t] += v;
        __syncthreads();
    }
    int run = (t == 0) ? 0 : partial[t - 1];
    #pragma unroll
    for (int i = 0; i < 32; i++) {
        row_ptr[base + i] = run;
        row_fill[base + i] = run;
        run += local[i];
    }
    if (t == 255) row_ptr[NNODES] = run;
}

__global__ void scatter_edges(const int* __restrict__ src, const int* __restrict__ dst, int E,
                              int* __restrict__ row_fill, int* __restrict__ col_idx)
{
    int tid = blockIdx.x * blockDim.x + threadIdx.x;
    if (tid < E) {
        int pos = atomicAdd(&row_fill[dst[tid]], 1);
        col_idx[pos] = src[tid];
    }
}

// ---------------- per-layer: hl = h@W^T+b ; gh = h@Whh^T+bhh (fused, width 256) ----
__global__ __launch_bounds__(256)
void layer_pre(const float* __restrict__ h,
               const float* __restrict__ Wt,   // [64][256] for this layer
               const float* __restrict__ bA,   // conv_b   [64]
               const float* __restrict__ bH,   // gru_bhh  [192]
               float* __restrict__ hl, float* __restrict__ gh)
{
    __shared__ float ht[16][64];
    int c = threadIdx.x;
    int row0 = blockIdx.x * 16;
    ((float4*)ht)[c] = ((const float4*)(h + row0 * 64))[c];
    __syncthreads();
    float bias = (c < 64) ? bA[c] : bH[c - 64];
    float acc[16];
    #pragma unroll
    for (int j = 0; j < 16; j++) acc[j] = bias;
    #pragma unroll 8
    for (int k = 0; k < 64; k++) {
        float w = Wt[k * 256 + c];
        #pragma unroll
        for (int j = 0; j < 16; j++) acc[j] = fmaf(ht[j][k], w, acc[j]);
    }
    if (c < 64) {
        #pragma unroll
        for (int j = 0; j < 16; j++) hl[(row0 + j) * 64 + c] = acc[j];
    } else {
        int cc = c - 64;
        #pragma unroll
        for (int j = 0; j < 16; j++) gh[(row0 + j) * 192 + cc] = acc[j];
    }
}

// ---------------- GRU gates with fused aggregation ----------------
__device__ __forceinline__ float sigmoidf_(float x) { return 1.f / (1.f + __expf(-x)); }
__device__ __forceinline__ float tanhf_(float x) {
    float e = __expf(-2.f * fabsf(x));
    float t = (1.f - e) / (1.f + e);
    return copysignf(t, x);
}

__global__ __launch_bounds__(256)
void layer_gru_agg(const float* __restrict__ hl,
                   const int* __restrict__ row_ptr,
                   const int* __restrict__ col_idx,
                   const float* __restrict__ WtI_l,  // [64][192]
                   const float* __restrict__ bih,    // [192]
                   const float* __restrict__ gh,
                   float* __restrict__ h)
{
    __shared__ float at[16][64];
    int tid = threadIdx.x;
    int d = tid & 63, rg = tid >> 6;   // rg = wave id
    int row0 = blockIdx.x * 16;
    // aggregation: each wave owns 4 of the block's 16 nodes
    #pragma unroll
    for (int jj = 0; jj < 4; jj++) {
        int node = row0 + rg * 4 + jj;
        int s0 = row_ptr[node], s1 = row_ptr[node + 1];
        float acc = hl[node * 64 + d];              // self loop
        for (int e = s0; e < s1; ++e)
            acc += hl[col_idx[e] * 64 + d];
        at[rg * 4 + jj][d] = acc;
    }
    __syncthreads();
    float ar[4], az[4], an[4];
    float br = bih[d], bz = bih[64 + d], bn = bih[128 + d];
    #pragma unroll
    for (int j = 0; j < 4; j++) { ar[j] = br; az[j] = bz; an[j] = bn; }
    #pragma unroll 8
    for (int k = 0; k < 64; k++) {
        float wr = WtI_l[k * 192 + d];
        float wz = WtI_l[k * 192 + 64 + d];
        float wn = WtI_l[k * 192 + 128 + d];
        #pragma unroll
        for (int j = 0; j < 4; j++) {
            float av = at[rg + 4 * j][k];
            ar[j] = fmaf(av, wr, ar[j]);
            az[j] = fmaf(av, wz, az[j]);
            an[j] = fmaf(av, wn, an[j]);
        }
    }
    #pragma unroll
    for (int j = 0; j < 4; j++) {
        int row = row0 + rg + 4 * j;
        float ghr = gh[row * 192 + d];
        float ghz = gh[row * 192 + 64 + d];
        float ghn = gh[row * 192 + 128 + d];
        float hv  = h[row * 64 + d];
        float r = sigmoidf_(ar[j] + ghr);
        float z = sigmoidf_(az[j] + ghz);
        float n = tanhf_(an[j] + r * ghn);
        float hn = (1.f - z) * n + z * hv;
        h[row * 64 + d] = fmaxf(hn, 0.f);
    }
}

// ---------------- MLP: h = relu(h@W^T+b), in place ----------------
__global__ __launch_bounds__(256)
void mlp_layer(const float* __restrict__ WtM_m,  // [64][64]
               const float* __restrict__ b,      // [64]
               float* __restrict__ h)
{
    __shared__ float ht[16][64];
    int tid = threadIdx.x;
    int d = tid & 63, rg = tid >> 6;
    int row0 = blockIdx.x * 16;
    ((float4*)ht)[tid] = ((const float4*)(h + row0 * 64))[tid];
    __syncthreads();
    float acc[4];
    float bias = b[d];
    #pragma unroll
    for (int j = 0; j < 4; j++) acc[j] = bias;
    #pragma unroll 8
    for (int k = 0; k < 64; k++) {
        float w = WtM_m[k * 64 + d];
        #pragma unroll
        for (int j = 0; j < 4; j++) acc[j] = fmaf(ht[rg + 4 * j][k], w, acc[j]);
    }
    #pragma unroll
    for (int j = 0; j < 4; j++) {
        int row = row0 + rg + 4 * j;
        h[row * 64 + d] = fmaxf(acc[j], 0.f);
    }
}

// ---------------- split h (f32) -> h_hi + h_lo (bf16, RNE) ----------------
__device__ __forceinline__ unsigned short f2bf_rne(float x) {
    unsigned int u = __float_as_uint(x);
    u += 0x7fffu + ((u >> 16) & 1u);
    return (unsigned short)(u >> 16);
}
__device__ __forceinline__ float bf2f(unsigned short b) {
    return __uint_as_float(((unsigned int)b) << 16);
}

__global__ __launch_bounds__(256)
void split_bf16(const float* __restrict__ h,
                unsigned short* __restrict__ h_hi,
                unsigned short* __restrict__ h_lo)
{
    int tid = blockIdx.x * blockDim.x + threadIdx.x;   // one per element
    float x = h[tid];
    unsigned short hi = f2bf_rne(x);
    float r = x - bf2f(hi);
    h_hi[tid] = hi;
    h_lo[tid] = f2bf_rne(r);
}

// ---------------- final: out = h @ h^T via MFMA bf16 x3 (hi/lo split) -------
// block = 4 waves, 128x128 output tile; wave quadrant 64x64 = 2x2 mfma 32x32 tiles.
// A/B frags loaded straight from global (h_hi/h_lo are 2MB total -> L2-resident).
// 32x32x16_bf16 A/B frag: lane l -> row/col = l&31, k = (l>>5)*8 + e.
// C/D (m74-verified): col = lane&31, row = (reg&3) + 8*(reg>>2) + 4*(lane>>5).
__global__ __launch_bounds__(256)
void simmat_mfma(const unsigned short* __restrict__ h_hi,
                 const unsigned short* __restrict__ h_lo,
                 float* __restrict__ out)
{
    int tid = threadIdx.x;
    int l = tid & 63, w = tid >> 6;
    int rbase = blockIdx.y * 128 + (w >> 1) * 64;   // wave's A rows
    int cbase = blockIdx.x * 128 + (w & 1) * 64;    // wave's B cols (nodes)
    int lr = l & 31;
    int ko = (l >> 5) * 8;

    const unsigned short* pa = h_hi + (rbase + lr) * 64 + ko;
    const unsigned short* pb = h_hi + (cbase + lr) * 64 + ko;
    const unsigned short* qa = h_lo + (rbase + lr) * 64 + ko;
    const unsigned short* qb = h_lo + (cbase + lr) * 64 + ko;

    facc16 acc[2][2];
    #pragma unroll
    for (int i = 0; i < 2; i++)
        #pragma unroll
        for (int j = 0; j < 2; j++) acc[i][j] = (facc16)(0.f);

    #pragma unroll
    for (int kk = 0; kk < 64; kk += 16) {
        bfrag8 ahi[2], alo[2], bhi[2], blo[2];
        #pragma unroll
        for (int i = 0; i < 2; i++) {
            ahi[i] = *(const bfrag8*)(pa + i * 32 * 64 + kk);
            alo[i] = *(const bfrag8*)(qa + i * 32 * 64 + kk);
            bhi[i] = *(const bfrag8*)(pb + i * 32 * 64 + kk);
            blo[i] = *(const bfrag8*)(qb + i * 32 * 64 + kk);
        }
        #pragma unroll
        for (int i = 0; i < 2; i++)
            #pragma unroll
            for (int j = 0; j < 2; j++) {
                acc[i][j] = __builtin_amdgcn_mfma_f32_32x32x16_bf16(ahi[i], bhi[j], acc[i][j], 0, 0, 0);
                acc[i][j] = __builtin_amdgcn_mfma_f32_32x32x16_bf16(ahi[i], blo[j], acc[i][j], 0, 0, 0);
                acc[i][j] = __builtin_amdgcn_mfma_f32_32x32x16_bf16(alo[i], bhi[j], acc[i][j], 0, 0, 0);
            }
    }

    int crow0 = rbase + 4 * (l >> 5);
    int ccol0 = cbase + (l & 31);
    #pragma unroll
    for (int i = 0; i < 2; i++)
        #pragma unroll
        for (int j = 0; j < 2; j++) {
            #pragma unroll
            for (int reg = 0; reg < 16; reg++) {
                int row = crow0 + i * 32 + (reg & 3) + 8 * (reg >> 2);
                int col = ccol0 + j * 32;
                out[(size_t)row * 8192 + col] = acc[i][j][reg];
            }
        }
}

extern "C" void kernel_launch(void* const* d_in, const int* in_sizes, int n_in,
                              void* d_out, int out_size, void* d_ws, size_t ws_size,
                              hipStream_t stream)
{
    const float* node_feat = (const float*)d_in[0];
    const int*   edge_src  = (const int*)d_in[1];
    const int*   edge_dst  = (const int*)d_in[2];
    const float* conv_W    = (const float*)d_in[3];
    const float* conv_b    = (const float*)d_in[4];
    const float* gru_Wih   = (const float*)d_in[5];
    const float* gru_Whh   = (const float*)d_in[6];
    const float* gru_bih   = (const float*)d_in[7];
    const float* gru_bhh   = (const float*)d_in[8];
    const float* mlp_W     = (const float*)d_in[9];
    const float* mlp_b     = (const float*)d_in[10];
    int E = in_sizes[1];
    float* out = (float*)d_out;

    // workspace carve (~15 MB total)
    float* ws  = (float*)d_ws;
    float* h   = ws;                          // 8192*64
    float* hl  = h  + NNODES * DDIM;          // 8192*64
    float* gh  = hl + NNODES * DDIM;          // 8192*192
    float* WtA = gh + NNODES * 192;           // 9*64*256
    float* WtI = WtA + NLAYER * 64 * 256;     // 9*64*192
    float* WtM = WtI + NLAYER * 64 * 192;     // 3*64*64
    int* counts   = (int*)(WtM + NMLP * 64 * 64);  // 8192
    int* row_ptr  = counts + NNODES;               // 8193
    int* row_fill = row_ptr + NNODES + 1;          // 8192
    int* col_idx  = row_fill + NNODES;             // E
    unsigned short* h_hi = (unsigned short*)((((uintptr_t)(col_idx + E)) + 15) & ~(uintptr_t)15);
    unsigned short* h_lo = h_hi + NNODES * DDIM;   // each 1 MB, 16B-aligned

    prep_weights<<<1056, 256, 0, stream>>>(conv_W, gru_Whh, gru_Wih, mlp_W, WtA, WtI, WtM);
    init_h<<<(NNODES * DDIM + 255) / 256, 256, 0, stream>>>(node_feat, h, counts);
    count_deg<<<(E + 255) / 256, 256, 0, stream>>>(edge_dst, E, counts);
    scan_deg<<<1, 256, 0, stream>>>(counts, row_ptr, row_fill);
    scatter_edges<<<(E + 255) / 256, 256, 0, stream>>>(edge_src, edge_dst, E, row_fill, col_idx);

    for (int l = 0; l < NLAYER; l++) {
        layer_pre<<<NNODES / 16, 256, 0, stream>>>(h, WtA + l * 16384,
                                                   conv_b + l * 64, gru_bhh + l * 192, hl, gh);
        layer_gru_agg<<<NNODES / 16, 256, 0, stream>>>(hl, row_ptr, col_idx,
                                                       WtI + l * 12288,
                                                       gru_bih + l * 192, gh, h);
    }
    for (int m = 0; m < NMLP; m++) {
        mlp_layer<<<NNODES / 16, 256, 0, stream>>>(WtM + m * 4096, mlp_b + m * 64, h);
    }
    split_bf16<<<NNODES * DDIM / 256, 256, 0, stream>>>(h, h_hi, h_lo);
    dim3 g(64, 64);
    simmat_mfma<<<g, 256, 0, stream>>>(h_hi, h_lo, out);
}

// Round 12
// 772.964 us; speedup vs baseline: 1.5378x; 1.5378x over previous
//
#include <hip/hip_runtime.h>
#include <math.h>

#define NNODES 8192
#define DDIM   64
#define NLAYER 9
#define NMLP   3

typedef short bfrag8 __attribute__((ext_vector_type(8)));   // 8 bf16 = 4 VGPR
typedef float facc16 __attribute__((ext_vector_type(16)));  // 32x32 C/D

// ---------------- weight transpose prep (once per launch) ----------------
__global__ void prep_weights(const float* __restrict__ conv_W,
                             const float* __restrict__ gru_Whh,
                             const float* __restrict__ gru_Wih,
                             const float* __restrict__ mlp_W,
                             float* __restrict__ WtA,
                             float* __restrict__ WtI,
                             float* __restrict__ WtM)
{
    int tid = blockIdx.x * blockDim.x + threadIdx.x;
    const int nA = NLAYER * 64 * 256;   // 147456
    const int nI = NLAYER * 64 * 192;   // 110592
    const int nM = NMLP * 64 * 64;      // 12288
    if (tid < nA) {
        int l = tid / 16384, rem = tid % 16384;
        int k = rem / 256, c = rem % 256;
        float v = (c < 64) ? conv_W[l * 4096 + c * 64 + k]
                           : gru_Whh[l * 12288 + (c - 64) * 64 + k];
        WtA[tid] = v;
    } else if (tid < nA + nI) {
        int t = tid - nA;
        int l = t / 12288, rem = t % 12288;
        int k = rem / 192, c = rem % 192;
        WtI[t] = gru_Wih[l * 12288 + c * 64 + k];
    } else if (tid < nA + nI + nM) {
        int t = tid - nA - nI;
        int m = t / 4096, rem = t % 4096;
        int k = rem / 64, c = rem % 64;
        WtM[t] = mlp_W[m * 4096 + c * 64 + k];
    }
}

// ---------------- h0 init + degree-count zero ----------------
__global__ void init_h(const float* __restrict__ node_feat,
                       float* __restrict__ h, int* __restrict__ counts)
{
    int tid = blockIdx.x * blockDim.x + threadIdx.x;
    if (tid < NNODES * DDIM) {
        int n = tid >> 6, d = tid & 63;
        h[tid] = (d == 0) ? node_feat[n] : 0.f;
    }
    if (tid < NNODES) counts[tid] = 0;
}

// ---------------- CSC build (by dst) ----------------
__global__ void count_deg(const int* __restrict__ dst, int E, int* __restrict__ counts)
{
    int tid = blockIdx.x * blockDim.x + threadIdx.x;
    if (tid < E) atomicAdd(&counts[dst[tid]], 1);
}

__global__ void scan_deg(const int* __restrict__ counts,
                         int* __restrict__ row_ptr, int* __restrict__ row_fill)
{
    __shared__ int partial[256];
    int t = threadIdx.x;
    int local[32];
    int base = t * 32;
    int s = 0;
    #pragma unroll
    for (int i = 0; i < 32; i++) { local[i] = counts[base + i]; s += local[i]; }
    partial[t] = s;
    __syncthreads();
    for (int off = 1; off < 256; off <<= 1) {
        int v = (t >= off) ? partial[t - off] : 0;
        __syncthreads();
        partial[t] += v;
        __syncthreads();
    }
    int run = (t == 0) ? 0 : partial[t - 1];
    #pragma unroll
    for (int i = 0; i < 32; i++) {
        row_ptr[base + i] = run;
        row_fill[base + i] = run;
        run += local[i];
    }
    if (t == 255) row_ptr[NNODES] = run;
}

__global__ void scatter_edges(const int* __restrict__ src, const int* __restrict__ dst, int E,
                              int* __restrict__ row_fill, int* __restrict__ col_idx)
{
    int tid = blockIdx.x * blockDim.x + threadIdx.x;
    if (tid < E) {
        int pos = atomicAdd(&row_fill[dst[tid]], 1);
        col_idx[pos] = src[tid];
    }
}

// ---------------- per-layer: hl = h@W^T+b ; gh = h@Whh^T+bhh ------------------
// 4 rows/block, 2048 blocks -> 8192 waves (8/SIMD) for latency hiding.
__global__ __launch_bounds__(256)
void layer_pre(const float* __restrict__ h,
               const float* __restrict__ Wt,   // [64][256] for this layer
               const float* __restrict__ bA,   // conv_b   [64]
               const float* __restrict__ bH,   // gru_bhh  [192]
               float* __restrict__ hl, float* __restrict__ gh)
{
    __shared__ float ht[4][64];
    int c = threadIdx.x;                 // output col 0..255
    int row0 = blockIdx.x * 4;
    ht[c >> 6][c & 63] = h[row0 * 64 + c];   // 1 KB coalesced
    __syncthreads();
    float bias = (c < 64) ? bA[c] : bH[c - 64];
    float acc0 = bias, acc1 = bias, acc2 = bias, acc3 = bias;
    #pragma unroll 8
    for (int k = 0; k < 64; k++) {
        float w = Wt[k * 256 + c];       // coalesced, L2-hot
        acc0 = fmaf(ht[0][k], w, acc0);  // LDS broadcast
        acc1 = fmaf(ht[1][k], w, acc1);
        acc2 = fmaf(ht[2][k], w, acc2);
        acc3 = fmaf(ht[3][k], w, acc3);
    }
    if (c < 64) {
        hl[(row0 + 0) * 64 + c] = acc0;
        hl[(row0 + 1) * 64 + c] = acc1;
        hl[(row0 + 2) * 64 + c] = acc2;
        hl[(row0 + 3) * 64 + c] = acc3;
    } else {
        int cc = c - 64;
        gh[(row0 + 0) * 192 + cc] = acc0;
        gh[(row0 + 1) * 192 + cc] = acc1;
        gh[(row0 + 2) * 192 + cc] = acc2;
        gh[(row0 + 3) * 192 + cc] = acc3;
    }
}

// ---------------- fused aggregation + GRU, 1 node/wave, 2048 blocks -----------
__device__ __forceinline__ float sigmoidf_(float x) { return 1.f / (1.f + __expf(-x)); }
__device__ __forceinline__ float tanhf_(float x) {
    float e = __expf(-2.f * fabsf(x));
    float t = (1.f - e) / (1.f + e);
    return copysignf(t, x);
}

__global__ __launch_bounds__(256)
void layer_gru_agg(const float* __restrict__ hl,
                   const int* __restrict__ row_ptr,
                   const int* __restrict__ col_idx,
                   const float* __restrict__ WtI_l,  // [64][192]
                   const float* __restrict__ bih,    // [192]
                   const float* __restrict__ gh,
                   float* __restrict__ h)
{
    __shared__ float at[4][64];
    __shared__ float wlds[64 * 192];     // 48 KB -> 3 blocks/CU (12 waves/CU)
    int tid = threadIdx.x;
    int d = tid & 63, rg = tid >> 6;     // wave rg owns node row0+rg
    int row0 = blockIdx.x * 4;
    // stage WtI (issued first; latency overlaps the gather below)
    #pragma unroll
    for (int i = 0; i < 12; i++)
        ((float4*)wlds)[tid + 256 * i] = ((const float4*)WtI_l)[tid + 256 * i];
    // aggregation: 1 node per wave, 4 gathers in flight
    int node = row0 + rg;
    int s0 = row_ptr[node], s1 = row_ptr[node + 1];
    float acc = hl[node * 64 + d];       // self loop
    int e = s0;
    for (; e + 4 <= s1; e += 4) {
        int n0 = col_idx[e], n1 = col_idx[e + 1], n2 = col_idx[e + 2], n3 = col_idx[e + 3];
        float v0 = hl[n0 * 64 + d];
        float v1 = hl[n1 * 64 + d];
        float v2 = hl[n2 * 64 + d];
        float v3 = hl[n3 * 64 + d];
        acc += (v0 + v1) + (v2 + v3);
    }
    for (; e < s1; ++e)
        acc += hl[col_idx[e] * 64 + d];
    at[rg][d] = acc;
    __syncthreads();
    // GRU gates: gi = at@Wih^T + bih
    float ar = bih[d], az = bih[64 + d], an = bih[128 + d];
    #pragma unroll 8
    for (int k = 0; k < 64; k++) {
        float av = at[rg][k];            // LDS broadcast
        ar = fmaf(av, wlds[k * 192 + d], ar);        // stride-1 lanes: conflict-free
        az = fmaf(av, wlds[k * 192 + 64 + d], az);
        an = fmaf(av, wlds[k * 192 + 128 + d], an);
    }
    float ghr = gh[node * 192 + d];
    float ghz = gh[node * 192 + 64 + d];
    float ghn = gh[node * 192 + 128 + d];
    float hv  = h[node * 64 + d];
    float r = sigmoidf_(ar + ghr);
    float z = sigmoidf_(az + ghz);
    float n = tanhf_(an + r * ghn);
    float hn = (1.f - z) * n + z * hv;
    h[node * 64 + d] = fmaxf(hn, 0.f);
}

// ---------------- MLP: h = relu(h@W^T+b), 4 rows/block, in place --------------
__global__ __launch_bounds__(256)
void mlp_layer(const float* __restrict__ WtM_m,  // [64][64]
               const float* __restrict__ b,      // [64]
               float* __restrict__ h)
{
    __shared__ float ht[4][64];
    int tid = threadIdx.x;
    int d = tid & 63, rg = tid >> 6;
    int row0 = blockIdx.x * 4;
    ht[tid >> 6][tid & 63] = h[row0 * 64 + tid];
    __syncthreads();
    float acc = b[d];
    #pragma unroll 8
    for (int k = 0; k < 64; k++)
        acc = fmaf(ht[rg][k], WtM_m[k * 64 + d], acc);
    h[(row0 + rg) * 64 + d] = fmaxf(acc, 0.f);
}

// ---------------- split h (f32) -> h_hi + h_lo (bf16, RNE) ----------------
__device__ __forceinline__ unsigned short f2bf_rne(float x) {
    unsigned int u = __float_as_uint(x);
    u += 0x7fffu + ((u >> 16) & 1u);
    return (unsigned short)(u >> 16);
}
__device__ __forceinline__ float bf2f(unsigned short b) {
    return __uint_as_float(((unsigned int)b) << 16);
}

__global__ __launch_bounds__(256)
void split_bf16(const float* __restrict__ h,
                unsigned short* __restrict__ h_hi,
                unsigned short* __restrict__ h_lo)
{
    int tid = blockIdx.x * blockDim.x + threadIdx.x;   // one per element
    float x = h[tid];
    unsigned short hi = f2bf_rne(x);
    float r = x - bf2f(hi);
    h_hi[tid] = hi;
    h_lo[tid] = f2bf_rne(r);
}

// ---------------- final: out = h @ h^T via MFMA bf16 x3 (hi/lo split) -------
// block = 4 waves, 128x128 output tile; wave quadrant 64x64 = 2x2 mfma 32x32 tiles.
// 32x32x16_bf16 A/B frag: lane l -> row/col = l&31, k = (l>>5)*8 + e.
// C/D (m74-verified): col = lane&31, row = (reg&3) + 8*(reg>>2) + 4*(lane>>5).
__global__ __launch_bounds__(256)
void simmat_mfma(const unsigned short* __restrict__ h_hi,
                 const unsigned short* __restrict__ h_lo,
                 float* __restrict__ out)
{
    int tid = threadIdx.x;
    int l = tid & 63, w = tid >> 6;
    int rbase = blockIdx.y * 128 + (w >> 1) * 64;   // wave's A rows
    int cbase = blockIdx.x * 128 + (w & 1) * 64;    // wave's B cols (nodes)
    int lr = l & 31;
    int ko = (l >> 5) * 8;

    const unsigned short* pa = h_hi + (rbase + lr) * 64 + ko;
    const unsigned short* pb = h_hi + (cbase + lr) * 64 + ko;
    const unsigned short* qa = h_lo + (rbase + lr) * 64 + ko;
    const unsigned short* qb = h_lo + (cbase + lr) * 64 + ko;

    facc16 acc[2][2];
    #pragma unroll
    for (int i = 0; i < 2; i++)
        #pragma unroll
        for (int j = 0; j < 2; j++) acc[i][j] = (facc16)(0.f);

    #pragma unroll
    for (int kk = 0; kk < 64; kk += 16) {
        bfrag8 ahi[2], alo[2], bhi[2], blo[2];
        #pragma unroll
        for (int i = 0; i < 2; i++) {
            ahi[i] = *(const bfrag8*)(pa + i * 32 * 64 + kk);
            alo[i] = *(const bfrag8*)(qa + i * 32 * 64 + kk);
            bhi[i] = *(const bfrag8*)(pb + i * 32 * 64 + kk);
            blo[i] = *(const bfrag8*)(qb + i * 32 * 64 + kk);
        }
        #pragma unroll
        for (int i = 0; i < 2; i++)
            #pragma unroll
            for (int j = 0; j < 2; j++) {
                acc[i][j] = __builtin_amdgcn_mfma_f32_32x32x16_bf16(ahi[i], bhi[j], acc[i][j], 0, 0, 0);
                acc[i][j] = __builtin_amdgcn_mfma_f32_32x32x16_bf16(ahi[i], blo[j], acc[i][j], 0, 0, 0);
                acc[i][j] = __builtin_amdgcn_mfma_f32_32x32x16_bf16(alo[i], bhi[j], acc[i][j], 0, 0, 0);
            }
    }

    int crow0 = rbase + 4 * (l >> 5);
    int ccol0 = cbase + (l & 31);
    #pragma unroll
    for (int i = 0; i < 2; i++)
        #pragma unroll
        for (int j = 0; j < 2; j++) {
            #pragma unroll
            for (int reg = 0; reg < 16; reg++) {
                int row = crow0 + i * 32 + (reg & 3) + 8 * (reg >> 2);
                int col = ccol0 + j * 32;
                out[(size_t)row * 8192 + col] = acc[i][j][reg];
            }
        }
}

extern "C" void kernel_launch(void* const* d_in, const int* in_sizes, int n_in,
                              void* d_out, int out_size, void* d_ws, size_t ws_size,
                              hipStream_t stream)
{
    const float* node_feat = (const float*)d_in[0];
    const int*   edge_src  = (const int*)d_in[1];
    const int*   edge_dst  = (const int*)d_in[2];
    const float* conv_W    = (const float*)d_in[3];
    const float* conv_b    = (const float*)d_in[4];
    const float* gru_Wih   = (const float*)d_in[5];
    const float* gru_Whh   = (const float*)d_in[6];
    const float* gru_bih   = (const float*)d_in[7];
    const float* gru_bhh   = (const float*)d_in[8];
    const float* mlp_W     = (const float*)d_in[9];
    const float* mlp_b     = (const float*)d_in[10];
    int E = in_sizes[1];
    float* out = (float*)d_out;

    // workspace carve (~15 MB total)
    float* ws  = (float*)d_ws;
    float* h   = ws;                          // 8192*64
    float* hl  = h  + NNODES * DDIM;          // 8192*64
    float* gh  = hl + NNODES * DDIM;          // 8192*192
    float* WtA = gh + NNODES * 192;           // 9*64*256
    float* WtI = WtA + NLAYER * 64 * 256;     // 9*64*192
    float* WtM = WtI + NLAYER * 64 * 192;     // 3*64*64
    int* counts   = (int*)(WtM + NMLP * 64 * 64);  // 8192
    int* row_ptr  = counts + NNODES;               // 8193
    int* row_fill = row_ptr + NNODES + 1;          // 8192
    int* col_idx  = row_fill + NNODES;             // E
    unsigned short* h_hi = (unsigned short*)((((uintptr_t)(col_idx + E)) + 15) & ~(uintptr_t)15);
    unsigned short* h_lo = h_hi + NNODES * DDIM;   // each 1 MB, 16B-aligned

    prep_weights<<<1056, 256, 0, stream>>>(conv_W, gru_Whh, gru_Wih, mlp_W, WtA, WtI, WtM);
    init_h<<<(NNODES * DDIM + 255) / 256, 256, 0, stream>>>(node_feat, h, counts);
    count_deg<<<(E + 255) / 256, 256, 0, stream>>>(edge_dst, E, counts);
    scan_deg<<<1, 256, 0, stream>>>(counts, row_ptr, row_fill);
    scatter_edges<<<(E + 255) / 256, 256, 0, stream>>>(edge_src, edge_dst, E, row_fill, col_idx);

    for (int l = 0; l < NLAYER; l++) {
        layer_pre<<<NNODES / 4, 256, 0, stream>>>(h, WtA + l * 16384,
                                                  conv_b + l * 64, gru_bhh + l * 192, hl, gh);
        layer_gru_agg<<<NNODES / 4, 256, 0, stream>>>(hl, row_ptr, col_idx,
                                                      WtI + l * 12288,
                                                      gru_bih + l * 192, gh, h);
    }
    for (int m = 0; m < NMLP; m++) {
        mlp_layer<<<NNODES / 4, 256, 0, stream>>>(WtM + m * 4096, mlp_b + m * 64, h);
    }
    split_bf16<<<NNODES * DDIM / 256, 256, 0, stream>>>(h, h_hi, h_lo);
    dim3 g(64, 64);
    simmat_mfma<<<g, 256, 0, stream>>>(h_hi, h_lo, out);
}

// Round 13
// 691.322 us; speedup vs baseline: 1.7195x; 1.1181x over previous
//
#include <hip/hip_runtime.h>
#include <math.h>

#define NNODES 8192
#define DDIM   64
#define NLAYER 9
#define NMLP   3

typedef short bfrag8 __attribute__((ext_vector_type(8)));   // 8 bf16 = 4 VGPR
typedef float facc16 __attribute__((ext_vector_type(16)));  // 32x32 C/D

// ---------------- weight transpose prep (once per launch) ----------------
__global__ void prep_weights(const float* __restrict__ conv_W,
                             const float* __restrict__ gru_Whh,
                             const float* __restrict__ gru_Wih,
                             const float* __restrict__ mlp_W,
                             float* __restrict__ WtA,
                             float* __restrict__ WtI,
                             float* __restrict__ WtM)
{
    int tid = blockIdx.x * blockDim.x + threadIdx.x;
    const int nA = NLAYER * 64 * 256;   // 147456
    const int nI = NLAYER * 64 * 192;   // 110592
    const int nM = NMLP * 64 * 64;      // 12288
    if (tid < nA) {
        int l = tid / 16384, rem = tid % 16384;
        int k = rem / 256, c = rem % 256;
        float v = (c < 64) ? conv_W[l * 4096 + c * 64 + k]
                           : gru_Whh[l * 12288 + (c - 64) * 64 + k];
        WtA[tid] = v;
    } else if (tid < nA + nI) {
        int t = tid - nA;
        int l = t / 12288, rem = t % 12288;
        int k = rem / 192, c = rem % 192;
        WtI[t] = gru_Wih[l * 12288 + c * 64 + k];
    } else if (tid < nA + nI + nM) {
        int t = tid - nA - nI;
        int m = t / 4096, rem = t % 4096;
        int k = rem / 64, c = rem % 64;
        WtM[t] = mlp_W[m * 4096 + c * 64 + k];
    }
}

// ---------------- h0 init + degree-count zero ----------------
__global__ void init_h(const float* __restrict__ node_feat,
                       float* __restrict__ h, int* __restrict__ counts)
{
    int tid = blockIdx.x * blockDim.x + threadIdx.x;
    if (tid < NNODES * DDIM) {
        int n = tid >> 6, d = tid & 63;
        h[tid] = (d == 0) ? node_feat[n] : 0.f;
    }
    if (tid < NNODES) counts[tid] = 0;
}

// ---------------- CSC build (by dst) ----------------
__global__ void count_deg(const int* __restrict__ dst, int E, int* __restrict__ counts)
{
    int tid = blockIdx.x * blockDim.x + threadIdx.x;
    if (tid < E) atomicAdd(&counts[dst[tid]], 1);
}

__global__ void scan_deg(const int* __restrict__ counts,
                         int* __restrict__ row_ptr, int* __restrict__ row_fill)
{
    __shared__ int partial[256];
    int t = threadIdx.x;
    int local[32];
    int base = t * 32;
    int s = 0;
    #pragma unroll
    for (int i = 0; i < 32; i++) { local[i] = counts[base + i]; s += local[i]; }
    partial[t] = s;
    __syncthreads();
    for (int off = 1; off < 256; off <<= 1) {
        int v = (t >= off) ? partial[t - off] : 0;
        __syncthreads();
        partial[t] += v;
        __syncthreads();
    }
    int run = (t == 0) ? 0 : partial[t - 1];
    #pragma unroll
    for (int i = 0; i < 32; i++) {
        row_ptr[base + i] = run;
        row_fill[base + i] = run;
        run += local[i];
    }
    if (t == 255) row_ptr[NNODES] = run;
}

__global__ void scatter_edges(const int* __restrict__ src, const int* __restrict__ dst, int E,
                              int* __restrict__ row_fill, int* __restrict__ col_idx)
{
    int tid = blockIdx.x * blockDim.x + threadIdx.x;
    if (tid < E) {
        int pos = atomicAdd(&row_fill[dst[tid]], 1);
        col_idx[pos] = src[tid];
    }
}

// ---------------- per-layer: hl = h@W^T+b ; gh = h@Whh^T+bhh ------------------
// 8 rows/block, 1024 blocks: halves redundant Wt L2 traffic vs 4-row version,
// keeps 4096 waves with 8-deep FMA ILP per thread.
__global__ __launch_bounds__(256)
void layer_pre(const float* __restrict__ h,
               const float* __restrict__ Wt,   // [64][256] for this layer
               const float* __restrict__ bA,   // conv_b   [64]
               const float* __restrict__ bH,   // gru_bhh  [192]
               float* __restrict__ hl, float* __restrict__ gh)
{
    __shared__ float ht[8][64];
    int c = threadIdx.x;                 // output col 0..255
    int row0 = blockIdx.x * 8;
    ((float2*)ht)[c] = ((const float2*)(h + row0 * 64))[c];   // 2 KB coalesced
    __syncthreads();
    float bias = (c < 64) ? bA[c] : bH[c - 64];
    float acc[8];
    #pragma unroll
    for (int r = 0; r < 8; r++) acc[r] = bias;
    #pragma unroll 8
    for (int k = 0; k < 64; k++) {
        float w = Wt[k * 256 + c];       // coalesced, L2-hot
        #pragma unroll
        for (int r = 0; r < 8; r++) acc[r] = fmaf(ht[r][k], w, acc[r]);
    }
    if (c < 64) {
        #pragma unroll
        for (int r = 0; r < 8; r++) hl[(row0 + r) * 64 + c] = acc[r];
    } else {
        int cc = c - 64;
        #pragma unroll
        for (int r = 0; r < 8; r++) gh[(row0 + r) * 192 + cc] = acc[r];
    }
}

// ---------------- fused aggregation + GRU, 2 nodes/wave, 1024 blocks ----------
// No weight LDS staging (was capping occupancy at 12 waves/CU): 4 waves/block
// read identical weight addresses -> L1-served after first wave.
__device__ __forceinline__ float sigmoidf_(float x) { return 1.f / (1.f + __expf(-x)); }
__device__ __forceinline__ float tanhf_(float x) {
    float e = __expf(-2.f * fabsf(x));
    float t = (1.f - e) / (1.f + e);
    return copysignf(t, x);
}

__global__ __launch_bounds__(256)
void layer_gru_agg(const float* __restrict__ hl,
                   const int* __restrict__ row_ptr,
                   const int* __restrict__ col_idx,
                   const float* __restrict__ WtI_l,  // [64][192]
                   const float* __restrict__ bih,    // [192]
                   const float* __restrict__ gh,
                   float* __restrict__ h)
{
    __shared__ float at[8][64];
    int tid = threadIdx.x;
    int d = tid & 63, rg = tid >> 6;     // wave rg owns nodes row0+2rg, row0+2rg+1
    int row0 = blockIdx.x * 8;
    #pragma unroll
    for (int s = 0; s < 2; s++) {
        int node = row0 + rg * 2 + s;
        int s0 = row_ptr[node], s1 = row_ptr[node + 1];
        float acc = hl[node * 64 + d];   // self loop
        int e = s0;
        for (; e + 4 <= s1; e += 4) {    // 4 gathers in flight
            int n0 = col_idx[e], n1 = col_idx[e + 1], n2 = col_idx[e + 2], n3 = col_idx[e + 3];
            float v0 = hl[n0 * 64 + d];
            float v1 = hl[n1 * 64 + d];
            float v2 = hl[n2 * 64 + d];
            float v3 = hl[n3 * 64 + d];
            acc += (v0 + v1) + (v2 + v3);
        }
        for (; e < s1; ++e)
            acc += hl[col_idx[e] * 64 + d];
        at[rg * 2 + s][d] = acc;
    }
    __syncthreads();
    // GRU gates: gi = at@Wih^T + bih
    float br = bih[d], bz = bih[64 + d], bn = bih[128 + d];
    float ar[2] = {br, br}, az[2] = {bz, bz}, an[2] = {bn, bn};
    #pragma unroll 8
    for (int k = 0; k < 64; k++) {
        float wr = WtI_l[k * 192 + d];
        float wz = WtI_l[k * 192 + 64 + d];
        float wn = WtI_l[k * 192 + 128 + d];
        #pragma unroll
        for (int s = 0; s < 2; s++) {
            float av = at[rg * 2 + s][k];    // LDS broadcast
            ar[s] = fmaf(av, wr, ar[s]);
            az[s] = fmaf(av, wz, az[s]);
            an[s] = fmaf(av, wn, an[s]);
        }
    }
    #pragma unroll
    for (int s = 0; s < 2; s++) {
        int node = row0 + rg * 2 + s;
        float ghr = gh[node * 192 + d];
        float ghz = gh[node * 192 + 64 + d];
        float ghn = gh[node * 192 + 128 + d];
        float hv  = h[node * 64 + d];
        float r = sigmoidf_(ar[s] + ghr);
        float z = sigmoidf_(az[s] + ghz);
        float n = tanhf_(an[s] + r * ghn);
        float hn = (1.f - z) * n + z * hv;
        h[node * 64 + d] = fmaxf(hn, 0.f);
    }
}

// ---------------- MLP: h = relu(h@W^T+b), 8 rows/block, in place --------------
__global__ __launch_bounds__(256)
void mlp_layer(const float* __restrict__ WtM_m,  // [64][64]
               const float* __restrict__ b,      // [64]
               float* __restrict__ h)
{
    __shared__ float ht[8][64];
    int tid = threadIdx.x;
    int d = tid & 63, rg = tid >> 6;
    int row0 = blockIdx.x * 8;
    ((float2*)ht)[tid] = ((const float2*)(h + row0 * 64))[tid];
    __syncthreads();
    float acc0 = b[d], acc1 = b[d];
    #pragma unroll 8
    for (int k = 0; k < 64; k++) {
        float w = WtM_m[k * 64 + d];
        acc0 = fmaf(ht[rg * 2 + 0][k], w, acc0);
        acc1 = fmaf(ht[rg * 2 + 1][k], w, acc1);
    }
    h[(row0 + rg * 2 + 0) * 64 + d] = fmaxf(acc0, 0.f);
    h[(row0 + rg * 2 + 1) * 64 + d] = fmaxf(acc1, 0.f);
}

// ---------------- split h (f32) -> h_hi + h_lo (bf16, RNE) ----------------
__device__ __forceinline__ unsigned short f2bf_rne(float x) {
    unsigned int u = __float_as_uint(x);
    u += 0x7fffu + ((u >> 16) & 1u);
    return (unsigned short)(u >> 16);
}
__device__ __forceinline__ float bf2f(unsigned short b) {
    return __uint_as_float(((unsigned int)b) << 16);
}

__global__ __launch_bounds__(256)
void split_bf16(const float* __restrict__ h,
                unsigned short* __restrict__ h_hi,
                unsigned short* __restrict__ h_lo)
{
    int tid = blockIdx.x * blockDim.x + threadIdx.x;   // one per element
    float x = h[tid];
    unsigned short hi = f2bf_rne(x);
    float r = x - bf2f(hi);
    h_hi[tid] = hi;
    h_lo[tid] = f2bf_rne(r);
}

// ---------------- final: out = h @ h^T via MFMA bf16 x3, LDS-staged ----------
// v2: panels staged in LDS with coalesced uint4 global loads (fixes the
// 32-requests-per-instruction scattered fragment loads of v1) + XOR swizzle.
// LDS row = 256 B = 16 uint4 slots (hi cols in slots 0-7, lo in 8-15),
// slot' = slot ^ (row & 15): bijective per row; fragment reads spread over
// all 16 bank-positions (residual <=4-way on b128, benign per G4/m201).
// 32x32x16_bf16 A/B frag: lane l -> row/col = l&31, k = (l>>5)*8 + e.
// C/D (m74-verified): col = lane&31, row = (reg&3) + 8*(reg>>2) + 4*(lane>>5).
__global__ __launch_bounds__(256)
void simmat_mfma(const unsigned short* __restrict__ h_hi,
                 const unsigned short* __restrict__ h_lo,
                 float* __restrict__ out)
{
    __shared__ uint4 smem[4096];        // 64 KB: PA = [0,2048), PB = [2048,4096)
    int tid = threadIdx.x;
    int l = tid & 63, w = tid >> 6;
    int by = blockIdx.y, bx = blockIdx.x;

    // stage both 128-row panels (hi+lo interleaved per row), fully coalesced
    #pragma unroll
    for (int q = 0; q < 8; q++) {
        int idx = tid + 256 * q;            // 0..2047
        int row = idx >> 4, seg = idx & 15;
        const unsigned short* baseAB = (seg < 8) ? h_hi : h_lo;
        uint4 va = ((const uint4*)(baseAB + (by * 128 + row) * 64))[seg & 7];
        smem[row * 16 + (seg ^ (row & 15))] = va;
        uint4 vb = ((const uint4*)(baseAB + (bx * 128 + row) * 64))[seg & 7];
        smem[2048 + row * 16 + (seg ^ (row & 15))] = vb;
    }
    __syncthreads();

    int lr = l & 31, hi5 = l >> 5;
    facc16 acc[2][2];
    #pragma unroll
    for (int i = 0; i < 2; i++)
        #pragma unroll
        for (int j = 0; j < 2; j++) acc[i][j] = (facc16)(0.f);

    #pragma unroll
    for (int kk = 0; kk < 64; kk += 16) {
        int kq = (kk >> 3) + hi5;           // 16B slot within hi half: 0..7
        bfrag8 ahi[2], alo[2], bhi[2], blo[2];
        #pragma unroll
        for (int i = 0; i < 2; i++) {
            int arow = (w >> 1) * 64 + i * 32 + lr;
            ahi[i] = *(const bfrag8*)&smem[arow * 16 + (kq ^ (arow & 15))];
            alo[i] = *(const bfrag8*)&smem[arow * 16 + ((8 + kq) ^ (arow & 15))];
            int brow = (w & 1) * 64 + i * 32 + lr;
            bhi[i] = *(const bfrag8*)&smem[2048 + brow * 16 + (kq ^ (brow & 15))];
            blo[i] = *(const bfrag8*)&smem[2048 + brow * 16 + ((8 + kq) ^ (brow & 15))];
        }
        #pragma unroll
        for (int i = 0; i < 2; i++)
            #pragma unroll
            for (int j = 0; j < 2; j++) {
                acc[i][j] = __builtin_amdgcn_mfma_f32_32x32x16_bf16(ahi[i], bhi[j], acc[i][j], 0, 0, 0);
                acc[i][j] = __builtin_amdgcn_mfma_f32_32x32x16_bf16(ahi[i], blo[j], acc[i][j], 0, 0, 0);
                acc[i][j] = __builtin_amdgcn_mfma_f32_32x32x16_bf16(alo[i], bhi[j], acc[i][j], 0, 0, 0);
            }
    }

    int rbase = by * 128 + (w >> 1) * 64;
    int cbase = bx * 128 + (w & 1) * 64;
    int crow0 = rbase + 4 * hi5;
    int ccol0 = cbase + lr;
    #pragma unroll
    for (int i = 0; i < 2; i++)
        #pragma unroll
        for (int j = 0; j < 2; j++) {
            #pragma unroll
            for (int reg = 0; reg < 16; reg++) {
                int row = crow0 + i * 32 + (reg & 3) + 8 * (reg >> 2);
                int col = ccol0 + j * 32;
                out[(size_t)row * 8192 + col] = acc[i][j][reg];
            }
        }
}

extern "C" void kernel_launch(void* const* d_in, const int* in_sizes, int n_in,
                              void* d_out, int out_size, void* d_ws, size_t ws_size,
                              hipStream_t stream)
{
    const float* node_feat = (const float*)d_in[0];
    const int*   edge_src  = (const int*)d_in[1];
    const int*   edge_dst  = (const int*)d_in[2];
    const float* conv_W    = (const float*)d_in[3];
    const float* conv_b    = (const float*)d_in[4];
    const float* gru_Wih   = (const float*)d_in[5];
    const float* gru_Whh   = (const float*)d_in[6];
    const float* gru_bih   = (const float*)d_in[7];
    const float* gru_bhh   = (const float*)d_in[8];
    const float* mlp_W     = (const float*)d_in[9];
    const float* mlp_b     = (const float*)d_in[10];
    int E = in_sizes[1];
    float* out = (float*)d_out;

    // workspace carve (~15 MB total)
    float* ws  = (float*)d_ws;
    float* h   = ws;                          // 8192*64
    float* hl  = h  + NNODES * DDIM;          // 8192*64
    float* gh  = hl + NNODES * DDIM;          // 8192*192
    float* WtA = gh + NNODES * 192;           // 9*64*256
    float* WtI = WtA + NLAYER * 64 * 256;     // 9*64*192
    float* WtM = WtI + NLAYER * 64 * 192;     // 3*64*64
    int* counts   = (int*)(WtM + NMLP * 64 * 64);  // 8192
    int* row_ptr  = counts + NNODES;               // 8193
    int* row_fill = row_ptr + NNODES + 1;          // 8192
    int* col_idx  = row_fill + NNODES;             // E
    unsigned short* h_hi = (unsigned short*)((((uintptr_t)(col_idx + E)) + 15) & ~(uintptr_t)15);
    unsigned short* h_lo = h_hi + NNODES * DDIM;   // each 1 MB, 16B-aligned

    prep_weights<<<1056, 256, 0, stream>>>(conv_W, gru_Whh, gru_Wih, mlp_W, WtA, WtI, WtM);
    init_h<<<(NNODES * DDIM + 255) / 256, 256, 0, stream>>>(node_feat, h, counts);
    count_deg<<<(E + 255) / 256, 256, 0, stream>>>(edge_dst, E, counts);
    scan_deg<<<1, 256, 0, stream>>>(counts, row_ptr, row_fill);
    scatter_edges<<<(E + 255) / 256, 256, 0, stream>>>(edge_src, edge_dst, E, row_fill, col_idx);

    for (int l = 0; l < NLAYER; l++) {
        layer_pre<<<NNODES / 8, 256, 0, stream>>>(h, WtA + l * 16384,
                                                  conv_b + l * 64, gru_bhh + l * 192, hl, gh);
        layer_gru_agg<<<NNODES / 8, 256, 0, stream>>>(hl, row_ptr, col_idx,
                                                      WtI + l * 12288,
                                                      gru_bih + l * 192, gh, h);
    }
    for (int m = 0; m < NMLP; m++) {
        mlp_layer<<<NNODES / 8, 256, 0, stream>>>(WtM + m * 4096, mlp_b + m * 64, h);
    }
    split_bf16<<<NNODES * DDIM / 256, 256, 0, stream>>>(h, h_hi, h_lo);
    dim3 g(64, 64);
    simmat_mfma<<<g, 256, 0, stream>>>(h_hi, h_lo, out);
}

// Round 14
// 678.404 us; speedup vs baseline: 1.7522x; 1.0190x over previous
//
#include <hip/hip_runtime.h>
#include <math.h>

#define NNODES 8192
#define DDIM   64
#define NLAYER 9
#define NMLP   3

typedef short bfrag8 __attribute__((ext_vector_type(8)));   // 8 bf16 = 4 VGPR
typedef float facc16 __attribute__((ext_vector_type(16)));  // 32x32 C/D

// ---------------- fused prologue: weight transposes + h0 init + degree count --
// grid = 2048*256 = 524288 threads (= N*D = E). counts pre-zeroed via memset.
__global__ void prep_all(const float* __restrict__ conv_W,
                         const float* __restrict__ gru_Whh,
                         const float* __restrict__ gru_Wih,
                         const float* __restrict__ mlp_W,
                         const float* __restrict__ node_feat,
                         const int* __restrict__ edge_dst,
                         float* __restrict__ WtA,
                         float* __restrict__ WtI,
                         float* __restrict__ WtM,
                         float* __restrict__ h0,
                         int* __restrict__ counts, int E)
{
    int tid = blockIdx.x * blockDim.x + threadIdx.x;
    const int nA = NLAYER * 64 * 256;   // 147456
    const int nI = NLAYER * 64 * 192;   // 110592
    const int nM = NMLP * 64 * 64;      // 12288
    if (tid < nA) {
        int l = tid / 16384, rem = tid % 16384;
        int k = rem / 256, c = rem % 256;
        WtA[tid] = (c < 64) ? conv_W[l * 4096 + c * 64 + k]
                            : gru_Whh[l * 12288 + (c - 64) * 64 + k];
    } else if (tid < nA + nI) {
        int t = tid - nA;
        int l = t / 12288, rem = t % 12288;
        int k = rem / 192, c = rem % 192;
        WtI[t] = gru_Wih[l * 12288 + c * 64 + k];
    } else if (tid < nA + nI + nM) {
        int t = tid - nA - nI;
        int m = t / 4096, rem = t % 4096;
        int k = rem / 64, c = rem % 64;
        WtM[t] = mlp_W[m * 4096 + c * 64 + k];
    }
    {   // h0 = pad(node_feat)  (tid covers exactly N*D)
        int n = tid >> 6, d = tid & 63;
        h0[tid] = (d == 0) ? node_feat[n] : 0.f;
    }
    if (tid < E) atomicAdd(&counts[edge_dst[tid]], 1);
}

__global__ void scan_deg(const int* __restrict__ counts,
                         int* __restrict__ row_ptr, int* __restrict__ row_fill)
{
    __shared__ int partial[256];
    int t = threadIdx.x;
    int local[32];
    int base = t * 32;
    int s = 0;
    #pragma unroll
    for (int i = 0; i < 32; i++) { local[i] = counts[base + i]; s += local[i]; }
    partial[t] = s;
    __syncthreads();
    for (int off = 1; off < 256; off <<= 1) {
        int v = (t >= off) ? partial[t - off] : 0;
        __syncthreads();
        partial[t] += v;
        __syncthreads();
    }
    int run = (t == 0) ? 0 : partial[t - 1];
    #pragma unroll
    for (int i = 0; i < 32; i++) {
        row_ptr[base + i] = run;
        row_fill[base + i] = run;
        run += local[i];
    }
    if (t == 255) row_ptr[NNODES] = run;
}

__global__ void scatter_edges(const int* __restrict__ src, const int* __restrict__ dst, int E,
                              int* __restrict__ row_fill, int* __restrict__ col_idx)
{
    int tid = blockIdx.x * blockDim.x + threadIdx.x;
    if (tid < E) {
        int pos = atomicAdd(&row_fill[dst[tid]], 1);
        col_idx[pos] = src[tid];
    }
}

// ---------------- whole conv layer in ONE kernel --------------------------
// Uses linearity: a = (gather h)@W^T + (deg+1)*b. Gather on h (complete from
// previous launch), then everything is row-local: a-GEMM, gi/gh-GEMMs, GRU.
// 8 rows/block, 1024 blocks; h double-buffered (gather reads hin, write hout).
__device__ __forceinline__ float sigmoidf_(float x) { return 1.f / (1.f + __expf(-x)); }
__device__ __forceinline__ float tanhf_(float x) {
    float e = __expf(-2.f * fabsf(x));
    float t = (1.f - e) / (1.f + e);
    return copysignf(t, x);
}

__global__ __launch_bounds__(256)
void layer_full(const float* __restrict__ hin,
                const int* __restrict__ row_ptr,
                const int* __restrict__ col_idx,
                const float* __restrict__ WtA_l,  // [64][256]: c<64 W, c>=64 Whh
                const float* __restrict__ WtI_l,  // [64][192]
                const float* __restrict__ cb,     // conv_b [64]
                const float* __restrict__ bih,    // [192]
                const float* __restrict__ bhh,    // [192]
                float* __restrict__ hout)
{
    __shared__ float hloc[8][64];
    __shared__ float agg[8][64];
    __shared__ float aLDS[8][64];
    int tid = threadIdx.x;
    int d = tid & 63, rg = tid >> 6;
    int row0 = blockIdx.x * 8;
    ((float2*)hloc)[tid] = ((const float2*)(hin + row0 * 64))[tid];  // local rows
    // gather on h: wave rg owns nodes row0+2rg, row0+2rg+1; 4 loads in flight
    #pragma unroll
    for (int s = 0; s < 2; s++) {
        int node = row0 + rg * 2 + s;
        int s0 = row_ptr[node], s1 = row_ptr[node + 1];
        float acc = hin[node * 64 + d];            // self loop
        int e = s0;
        for (; e + 4 <= s1; e += 4) {
            int n0 = col_idx[e], n1 = col_idx[e + 1], n2 = col_idx[e + 2], n3 = col_idx[e + 3];
            float v0 = hin[n0 * 64 + d];
            float v1 = hin[n1 * 64 + d];
            float v2 = hin[n2 * 64 + d];
            float v3 = hin[n3 * 64 + d];
            acc += (v0 + v1) + (v2 + v3);
        }
        for (; e < s1; ++e)
            acc += hin[col_idx[e] * 64 + d];
        agg[rg * 2 + s][d] = acc;
    }
    __syncthreads();
    // phase 1: a = agg@W^T + (deg+1)*conv_b
    {
        int r0 = rg * 2, r1 = rg * 2 + 1;
        float deg0 = (float)(row_ptr[row0 + r0 + 1] - row_ptr[row0 + r0] + 1);
        float deg1 = (float)(row_ptr[row0 + r1 + 1] - row_ptr[row0 + r1] + 1);
        float cbd = cb[d];
        float a0 = deg0 * cbd, a1 = deg1 * cbd;
        #pragma unroll 8
        for (int k = 0; k < 64; k++) {
            float w = WtA_l[k * 256 + d];          // W col d, coalesced L2-hot
            a0 = fmaf(agg[r0][k], w, a0);
            a1 = fmaf(agg[r1][k], w, a1);
        }
        aLDS[r0][d] = a0;
        aLDS[r1][d] = a1;
    }
    __syncthreads();
    // phase 2: gi = a@Wih^T + bih ; gh = h@Whh^T + bhh ; GRU combine ; relu
    float gir[2], giz[2], gin[2], ghr[2], ghz[2], ghn[2];
    {
        float br = bih[d], bz = bih[64 + d], bn = bih[128 + d];
        float cr = bhh[d], cz = bhh[64 + d], cn = bhh[128 + d];
        #pragma unroll
        for (int s = 0; s < 2; s++) { gir[s]=br; giz[s]=bz; gin[s]=bn; ghr[s]=cr; ghz[s]=cz; ghn[s]=cn; }
    }
    #pragma unroll 4
    for (int k = 0; k < 64; k++) {
        float wir = WtI_l[k * 192 + d];
        float wiz = WtI_l[k * 192 + 64 + d];
        float win = WtI_l[k * 192 + 128 + d];
        float whr = WtA_l[k * 256 + 64 + d];
        float whz = WtA_l[k * 256 + 128 + d];
        float whn = WtA_l[k * 256 + 192 + d];
        #pragma unroll
        for (int s = 0; s < 2; s++) {
            float av = aLDS[rg * 2 + s][k];        // LDS broadcast
            float hv = hloc[rg * 2 + s][k];
            gir[s] = fmaf(av, wir, gir[s]);
            giz[s] = fmaf(av, wiz, giz[s]);
            gin[s] = fmaf(av, win, gin[s]);
            ghr[s] = fmaf(hv, whr, ghr[s]);
            ghz[s] = fmaf(hv, whz, ghz[s]);
            ghn[s] = fmaf(hv, whn, ghn[s]);
        }
    }
    #pragma unroll
    for (int s = 0; s < 2; s++) {
        int row = row0 + rg * 2 + s;
        float r = sigmoidf_(gir[s] + ghr[s]);
        float z = sigmoidf_(giz[s] + ghz[s]);
        float n = tanhf_(gin[s] + r * ghn[s]);
        float hv = hloc[rg * 2 + s][d];
        float hnew = (1.f - z) * n + z * hv;
        hout[row * 64 + d] = fmaxf(hnew, 0.f);
    }
}

// ---------------- 3 MLP layers + bf16 split, fused, row-local ---------------
__device__ __forceinline__ unsigned short f2bf_rne(float x) {
    unsigned int u = __float_as_uint(x);
    u += 0x7fffu + ((u >> 16) & 1u);
    return (unsigned short)(u >> 16);
}
__device__ __forceinline__ float bf2f(unsigned short b) {
    return __uint_as_float(((unsigned int)b) << 16);
}

__global__ __launch_bounds__(256)
void mlp_split(const float* __restrict__ WtM,   // [3][64][64] (k-major)
               const float* __restrict__ mlp_b, // [3][64]
               const float* __restrict__ hin,
               unsigned short* __restrict__ h_hi,
               unsigned short* __restrict__ h_lo)
{
    __shared__ float buf0[8][64], buf1[8][64];
    int tid = threadIdx.x, d = tid & 63, rg = tid >> 6;
    int row0 = blockIdx.x * 8;
    ((float2*)buf0)[tid] = ((const float2*)(hin + row0 * 64))[tid];
    __syncthreads();
    #pragma unroll
    for (int m = 0; m < 3; m++) {
        const float* Wm = WtM + m * 4096;
        float bias = mlp_b[m * 64 + d];
        float (*src)[64] = (m & 1) ? buf1 : buf0;
        float (*dst)[64] = (m & 1) ? buf0 : buf1;
        float a0 = bias, a1 = bias;
        #pragma unroll 8
        for (int k = 0; k < 64; k++) {
            float w = Wm[k * 64 + d];
            a0 = fmaf(src[rg * 2 + 0][k], w, a0);
            a1 = fmaf(src[rg * 2 + 1][k], w, a1);
        }
        dst[rg * 2 + 0][d] = fmaxf(a0, 0.f);
        dst[rg * 2 + 1][d] = fmaxf(a1, 0.f);
        __syncthreads();
    }
    // final result in buf1 (m=2 wrote buf1)
    #pragma unroll
    for (int s = 0; s < 2; s++) {
        int row = row0 + rg * 2 + s;
        float x = buf1[rg * 2 + s][d];
        unsigned short hi = f2bf_rne(x);
        h_hi[row * 64 + d] = hi;
        h_lo[row * 64 + d] = f2bf_rne(x - bf2f(hi));
    }
}

// ---------------- final: out = h @ h^T via MFMA bf16 x3, LDS-staged ----------
// (unchanged from R13) panels staged via coalesced uint4 loads + XOR swizzle.
// 32x32x16_bf16 A/B frag: lane l -> row/col = l&31, k = (l>>5)*8 + e.
// C/D (m74-verified): col = lane&31, row = (reg&3) + 8*(reg>>2) + 4*(lane>>5).
__global__ __launch_bounds__(256)
void simmat_mfma(const unsigned short* __restrict__ h_hi,
                 const unsigned short* __restrict__ h_lo,
                 float* __restrict__ out)
{
    __shared__ uint4 smem[4096];        // 64 KB: PA = [0,2048), PB = [2048,4096)
    int tid = threadIdx.x;
    int l = tid & 63, w = tid >> 6;
    int by = blockIdx.y, bx = blockIdx.x;

    #pragma unroll
    for (int q = 0; q < 8; q++) {
        int idx = tid + 256 * q;            // 0..2047
        int row = idx >> 4, seg = idx & 15;
        const unsigned short* baseAB = (seg < 8) ? h_hi : h_lo;
        uint4 va = ((const uint4*)(baseAB + (by * 128 + row) * 64))[seg & 7];
        smem[row * 16 + (seg ^ (row & 15))] = va;
        uint4 vb = ((const uint4*)(baseAB + (bx * 128 + row) * 64))[seg & 7];
        smem[2048 + row * 16 + (seg ^ (row & 15))] = vb;
    }
    __syncthreads();

    int lr = l & 31, hi5 = l >> 5;
    facc16 acc[2][2];
    #pragma unroll
    for (int i = 0; i < 2; i++)
        #pragma unroll
        for (int j = 0; j < 2; j++) acc[i][j] = (facc16)(0.f);

    #pragma unroll
    for (int kk = 0; kk < 64; kk += 16) {
        int kq = (kk >> 3) + hi5;           // 16B slot within hi half: 0..7
        bfrag8 ahi[2], alo[2], bhi[2], blo[2];
        #pragma unroll
        for (int i = 0; i < 2; i++) {
            int arow = (w >> 1) * 64 + i * 32 + lr;
            ahi[i] = *(const bfrag8*)&smem[arow * 16 + (kq ^ (arow & 15))];
            alo[i] = *(const bfrag8*)&smem[arow * 16 + ((8 + kq) ^ (arow & 15))];
            int brow = (w & 1) * 64 + i * 32 + lr;
            bhi[i] = *(const bfrag8*)&smem[2048 + brow * 16 + (kq ^ (brow & 15))];
            blo[i] = *(const bfrag8*)&smem[2048 + brow * 16 + ((8 + kq) ^ (brow & 15))];
        }
        #pragma unroll
        for (int i = 0; i < 2; i++)
            #pragma unroll
            for (int j = 0; j < 2; j++) {
                acc[i][j] = __builtin_amdgcn_mfma_f32_32x32x16_bf16(ahi[i], bhi[j], acc[i][j], 0, 0, 0);
                acc[i][j] = __builtin_amdgcn_mfma_f32_32x32x16_bf16(ahi[i], blo[j], acc[i][j], 0, 0, 0);
                acc[i][j] = __builtin_amdgcn_mfma_f32_32x32x16_bf16(alo[i], bhi[j], acc[i][j], 0, 0, 0);
            }
    }

    int rbase = by * 128 + (w >> 1) * 64;
    int cbase = bx * 128 + (w & 1) * 64;
    int crow0 = rbase + 4 * hi5;
    int ccol0 = cbase + lr;
    #pragma unroll
    for (int i = 0; i < 2; i++)
        #pragma unroll
        for (int j = 0; j < 2; j++) {
            #pragma unroll
            for (int reg = 0; reg < 16; reg++) {
                int row = crow0 + i * 32 + (reg & 3) + 8 * (reg >> 2);
                int col = ccol0 + j * 32;
                out[(size_t)row * 8192 + col] = acc[i][j][reg];
            }
        }
}

extern "C" void kernel_launch(void* const* d_in, const int* in_sizes, int n_in,
                              void* d_out, int out_size, void* d_ws, size_t ws_size,
                              hipStream_t stream)
{
    const float* node_feat = (const float*)d_in[0];
    const int*   edge_src  = (const int*)d_in[1];
    const int*   edge_dst  = (const int*)d_in[2];
    const float* conv_W    = (const float*)d_in[3];
    const float* conv_b    = (const float*)d_in[4];
    const float* gru_Wih   = (const float*)d_in[5];
    const float* gru_Whh   = (const float*)d_in[6];
    const float* gru_bih   = (const float*)d_in[7];
    const float* gru_bhh   = (const float*)d_in[8];
    const float* mlp_W     = (const float*)d_in[9];
    const float* mlp_b     = (const float*)d_in[10];
    int E = in_sizes[1];
    float* out = (float*)d_out;

    // workspace carve
    float* ws  = (float*)d_ws;
    float* h0  = ws;                          // 8192*64
    float* h1  = h0 + NNODES * DDIM;          // 8192*64
    float* WtA = h1 + NNODES * DDIM;          // 9*64*256
    float* WtI = WtA + NLAYER * 64 * 256;     // 9*64*192
    float* WtM = WtI + NLAYER * 64 * 192;     // 3*64*64
    int* counts   = (int*)(WtM + NMLP * 64 * 64);  // 8192
    int* row_ptr  = counts + NNODES;               // 8193
    int* row_fill = row_ptr + NNODES + 1;          // 8192
    int* col_idx  = row_fill + NNODES;             // E
    unsigned short* h_hi = (unsigned short*)((((uintptr_t)(col_idx + E)) + 15) & ~(uintptr_t)15);
    unsigned short* h_lo = h_hi + NNODES * DDIM;   // each 1 MB, 16B-aligned

    hipMemsetAsync(counts, 0, NNODES * sizeof(int), stream);
    prep_all<<<2048, 256, 0, stream>>>(conv_W, gru_Whh, gru_Wih, mlp_W,
                                       node_feat, edge_dst,
                                       WtA, WtI, WtM, h0, counts, E);
    scan_deg<<<1, 256, 0, stream>>>(counts, row_ptr, row_fill);
    scatter_edges<<<(E + 255) / 256, 256, 0, stream>>>(edge_src, edge_dst, E, row_fill, col_idx);

    const float* cur = h0;
    float* nxt = h1;
    for (int l = 0; l < NLAYER; l++) {
        layer_full<<<NNODES / 8, 256, 0, stream>>>(cur, row_ptr, col_idx,
                                                   WtA + l * 16384, WtI + l * 12288,
                                                   conv_b + l * 64,
                                                   gru_bih + l * 192, gru_bhh + l * 192,
                                                   nxt);
        const float* t = cur; cur = nxt; nxt = (float*)t;
    }
    mlp_split<<<NNODES / 8, 256, 0, stream>>>(WtM, mlp_b, cur, h_hi, h_lo);
    dim3 g(64, 64);
    simmat_mfma<<<g, 256, 0, stream>>>(h_hi, h_lo, out);
}